// Round 2
// baseline (7494.406 us; speedup 1.0000x reference)
//
#include <hip/hip_runtime.h>
#include <hip/hip_bf16.h>
#include <math.h>

// ---------------------------------------------------------------------------
// TransformerModel: 12-layer causal linear-attention encoder.
// B=1, S=1024, D_MODEL=512, H=8, Dh=64, FF=2048.
// Round 2: all float tensors are fp32 (per reference dtypes). x is int32.
// Output: fp32 [h(1024x512), y_emo(1024x8)] concatenated.
// ---------------------------------------------------------------------------

#define S_LEN 1024
#define DM 512
#define NH 8
#define DH 64
#define DFF 2048
#define NLAYER 12
#define CHUNK 64
#define NCH (S_LEN / CHUNK)   // 16

// ---------------- activation codes ----------------
#define ACT_NONE 0
#define ACT_PHI  1
#define ACT_GELU 2

// ---------------- embedding gather ----------------
__global__ __launch_bounds__(256) void embed_kernel(
    const int* __restrict__ x,
    const float* __restrict__ t0, const float* __restrict__ t1,
    const float* __restrict__ t2, const float* __restrict__ t3,
    const float* __restrict__ t4, const float* __restrict__ t5,
    float* __restrict__ EMB)
{
    int s = blockIdx.x;
    __shared__ int xi[6];
    if (threadIdx.x < 6) xi[threadIdx.x] = x[s * 6 + threadIdx.x];
    __syncthreads();
    for (int j = threadIdx.x; j < 768; j += 256) {
        int i, off, width; const float* t; float sc;
        if (j < 32)       { i = 0; off = 0;   t = t0; sc = 5.656854249f;  width = 32;  }
        else if (j < 160) { i = 1; off = 32;  t = t1; sc = 11.3137085f;   width = 128; }
        else if (j < 416) { i = 2; off = 160; t = t2; sc = 16.0f;         width = 256; }
        else if (j < 672) { i = 3; off = 416; t = t3; sc = 16.0f;         width = 256; }
        else if (j < 704) { i = 4; off = 672; t = t4; sc = 5.656854249f;  width = 32;  }
        else              { i = 5; off = 704; t = t5; sc = 8.0f;          width = 64;  }
        EMB[s * 768 + j] = t[xi[i] * width + (j - off)] * sc;
    }
}

// ---------------- generic GEMM: C = act(A@W + bias) [+resid] [+pos-enc] ----------------
// A: f32 [M,K]; W: f32 [K,N]; bias: f32 [N]; resid: f32 [M,N] or null; C: f32 [M,N]
// BM=BN=64, BK=16, 256 threads, 4x4 microtile. M%64==0, N%64==0, K%16==0.
__global__ __launch_bounds__(256) void gemm_kernel(
    const float* __restrict__ A, const float* __restrict__ W,
    const float* __restrict__ bias, const float* __restrict__ resid,
    float* __restrict__ C, int M, int N, int K, int act, int add_pe)
{
    __shared__ float As[16][65];
    __shared__ float Bs[16][65];
    const int tid = threadIdx.x;
    const int tx = tid & 15, ty = tid >> 4;
    const int row0 = blockIdx.y * 64, col0 = blockIdx.x * 64;
    float acc[4][4] = {};
    for (int k0 = 0; k0 < K; k0 += 16) {
        #pragma unroll
        for (int i = 0; i < 4; ++i) {
            int idx = tid + i * 256;
            int r = idx >> 4, c = idx & 15;
            As[c][r] = A[(size_t)(row0 + r) * K + k0 + c];
        }
        #pragma unroll
        for (int i = 0; i < 4; ++i) {
            int idx = tid + i * 256;
            int r = idx >> 6, c = idx & 63;
            Bs[r][c] = W[(size_t)(k0 + r) * N + col0 + c];
        }
        __syncthreads();
        #pragma unroll
        for (int kk = 0; kk < 16; ++kk) {
            float a[4], b[4];
            #pragma unroll
            for (int i = 0; i < 4; ++i) a[i] = As[kk][ty * 4 + i];
            #pragma unroll
            for (int j = 0; j < 4; ++j) b[j] = Bs[kk][tx * 4 + j];
            #pragma unroll
            for (int i = 0; i < 4; ++i)
                #pragma unroll
                for (int j = 0; j < 4; ++j)
                    acc[i][j] += a[i] * b[j];
        }
        __syncthreads();
    }
    #pragma unroll
    for (int i = 0; i < 4; ++i) {
        int r = row0 + ty * 4 + i;
        #pragma unroll
        for (int j = 0; j < 4; ++j) {
            int c = col0 + tx * 4 + j;
            float v = acc[i][j] + bias[c];
            if (act == ACT_PHI)       v = (v > 0.0f) ? (v + 1.0f) : expf(v);
            else if (act == ACT_GELU) v = 0.5f * v * (1.0f + erff(v * 0.70710678118654752f));
            if (resid) v += resid[(size_t)r * N + c];
            if (add_pe) {
                float freq = expf((float)(c & ~1) * (-9.210340371976184f / 512.0f));
                float ang = (float)r * freq;
                v += (c & 1) ? cosf(ang) : sinf(ang);
            }
            C[(size_t)r * N + c] = v;
        }
    }
}

// ---------------- chunk stats: per (head, chunk) KV_c = K_c^T V_c, ksum_c ----------------
// K,V: f32 [S, 512]. KVC: [NCH][NH][64][64]; KSC: [NCH][NH][64]
__global__ __launch_bounds__(256) void chunk_stats_kernel(
    const float* __restrict__ Kb, const float* __restrict__ Vb,
    float* __restrict__ KVC, float* __restrict__ KSC)
{
    const int h = blockIdx.x >> 4, c = blockIdx.x & 15;
    const int tid = threadIdx.x;
    __shared__ float Ks[CHUNK][64];
    __shared__ float Vs[CHUNK][64];
    for (int i = tid; i < CHUNK * 64; i += 256) {
        int r = i >> 6, cc = i & 63;
        Ks[r][cc] = Kb[(size_t)(c * CHUNK + r) * DM + h * 64 + cc];
        Vs[r][cc] = Vb[(size_t)(c * CHUNK + r) * DM + h * 64 + cc];
    }
    __syncthreads();
    const int e = tid & 63, dg = tid >> 6;   // dg in [0,4): d range dg*16..+16
    float acc[16] = {};
    for (int t = 0; t < CHUNK; ++t) {
        float vv = Vs[t][e];
        #pragma unroll
        for (int i = 0; i < 16; ++i) acc[i] += Ks[t][dg * 16 + i] * vv;
    }
    float* out = KVC + ((size_t)(c * NH + h)) * 4096;
    #pragma unroll
    for (int i = 0; i < 16; ++i) out[(dg * 16 + i) * 64 + e] = acc[i];
    if (tid < 64) {
        float s = 0.0f;
        for (int t = 0; t < CHUNK; ++t) s += Ks[t][tid];
        KSC[(size_t)(c * NH + h) * 64 + tid] = s;
    }
}

// ---------------- exclusive prefix over chunks ----------------
__global__ __launch_bounds__(256) void prefix_kernel(
    const float* __restrict__ KVC, const float* __restrict__ KSC,
    float* __restrict__ KVP, float* __restrict__ KSP)
{
    const int h = blockIdx.x;
    const int tid = threadIdx.x;
    for (int i = tid; i < 4096; i += 256) {
        float run = 0.0f;
        for (int c = 0; c < NCH; ++c) {
            size_t idx = ((size_t)(c * NH + h)) * 4096 + i;
            KVP[idx] = run;
            run += KVC[idx];
        }
    }
    if (tid < 64) {
        float run = 0.0f;
        for (int c = 0; c < NCH; ++c) {
            size_t idx = (size_t)(c * NH + h) * 64 + tid;
            KSP[idx] = run;
            run += KSC[idx];
        }
    }
}

// ---------------- attention output per (head, chunk) ----------------
// out[s] = [ masked(Q Kᵀ) V + Q·KVP ] / (rowsum(masked QKᵀ) + Q·KSP + eps)
__global__ __launch_bounds__(256) void attn_out_kernel(
    const float* __restrict__ Qb, const float* __restrict__ Kb,
    const float* __restrict__ Vb, const float* __restrict__ KVP,
    const float* __restrict__ KSP, float* __restrict__ Ab)
{
    const int h = blockIdx.x >> 4, c = blockIdx.x & 15;
    const int tid = threadIdx.x;
    __shared__ float Qs[CHUNK][65];
    __shared__ float Ks[CHUNK][65];
    __shared__ float Vs[CHUNK][65];
    __shared__ float KSs[64];
    for (int i = tid; i < CHUNK * 64; i += 256) {
        int r = i >> 6, cc = i & 63;
        size_t g = (size_t)(c * CHUNK + r) * DM + h * 64 + cc;
        Qs[r][cc] = Qb[g];
        Ks[r][cc] = Kb[g];
        Vs[r][cc] = Vb[g];
    }
    if (tid < 64) KSs[tid] = KSP[(size_t)(c * NH + h) * 64 + tid];
    __syncthreads();

    const int s = tid >> 2;            // row in chunk
    const int e0 = (tid & 3) * 16;     // 16 output cols per thread
    float acc[16] = {};
    float den = 0.0f;

    // inter-chunk (state) part
    const float* kvp = KVP + ((size_t)(c * NH + h)) * 4096;
    for (int d = 0; d < 64; ++d) {
        float qd = Qs[s][d];
        den += qd * KSs[d];
        const float* row = kvp + d * 64 + e0;
        #pragma unroll
        for (int j = 0; j < 16; ++j) acc[j] += qd * row[j];
    }
    // intra-chunk causal part (t <= s)
    for (int t = 0; t <= s; ++t) {
        float sc = 0.0f;
        #pragma unroll
        for (int d = 0; d < 64; ++d) sc += Qs[s][d] * Ks[t][d];
        den += sc;
        #pragma unroll
        for (int j = 0; j < 16; ++j) acc[j] += sc * Vs[t][e0 + j];
    }
    float z = 1.0f / (den + 1e-6f);
    float* out = Ab + (size_t)(c * CHUNK + s) * DM + h * 64 + e0;
    #pragma unroll
    for (int j = 0; j < 16; ++j) out[j] = acc[j] * z;
}

// ---------------- layernorm (two-pass) ----------------
__device__ __forceinline__ float block_reduce_sum(float v, float* smem)
{
    #pragma unroll
    for (int o = 32; o > 0; o >>= 1) v += __shfl_down(v, o, 64);
    int w = threadIdx.x >> 6;
    if ((threadIdx.x & 63) == 0) smem[w] = v;
    __syncthreads();
    v = smem[0] + smem[1] + smem[2] + smem[3];
    __syncthreads();
    return v;
}

__global__ __launch_bounds__(256) void ln_kernel(
    const float* __restrict__ X, const float* __restrict__ g,
    const float* __restrict__ b, float* __restrict__ O)
{
    __shared__ float red[4];
    const int row = blockIdx.x;
    const float* x = X + (size_t)row * DM;
    const int t = threadIdx.x;
    float v0 = x[t], v1 = x[t + 256];
    float mean = block_reduce_sum(v0 + v1, red) * (1.0f / 512.0f);
    float d0 = v0 - mean, d1 = v1 - mean;
    float var = block_reduce_sum(d0 * d0 + d1 * d1, red) * (1.0f / 512.0f);
    float rs = 1.0f / sqrtf(var + 1e-5f);
    O[(size_t)row * DM + t]       = d0 * rs * g[t] + b[t];
    O[(size_t)row * DM + t + 256] = d1 * rs * g[t + 256] + b[t + 256];
}

// ---------------- emotion head: [1024,512] @ [512,8] + b ----------------
__global__ __launch_bounds__(256) void proj_emo_kernel(
    const float* __restrict__ HF, const float* __restrict__ pw,
    const float* __restrict__ pb, float* __restrict__ out)
{
    int idx = blockIdx.x * 256 + threadIdx.x;   // < 8192
    int r = idx >> 3, e = idx & 7;
    float acc = pb[e];
    const float* h = HF + (size_t)r * DM;
    for (int d = 0; d < DM; ++d) acc += h[d] * pw[d * 8 + e];
    out[idx] = acc;
}

// ---------------------------------------------------------------------------
extern "C" void kernel_launch(void* const* d_in, const int* in_sizes, int n_in,
                              void* d_out, int out_size, void* d_ws, size_t ws_size,
                              hipStream_t stream)
{
    const int*   x    = (const int*)d_in[0];
    const float* e0   = (const float*)d_in[1];
    const float* e1   = (const float*)d_in[2];
    const float* e2   = (const float*)d_in[3];
    const float* e3   = (const float*)d_in[4];
    const float* e4   = (const float*)d_in[5];
    const float* e5   = (const float*)d_in[6];
    const float* in_w = (const float*)d_in[7];
    const float* in_b = (const float*)d_in[8];
    const float* wq   = (const float*)d_in[9];
    const float* bq   = (const float*)d_in[10];
    const float* wk   = (const float*)d_in[11];
    const float* bk   = (const float*)d_in[12];
    const float* wv   = (const float*)d_in[13];
    const float* bv   = (const float*)d_in[14];
    const float* wo   = (const float*)d_in[15];
    const float* bo   = (const float*)d_in[16];
    const float* g1   = (const float*)d_in[17];
    const float* be1  = (const float*)d_in[18];
    const float* w1   = (const float*)d_in[19];
    const float* b1   = (const float*)d_in[20];
    const float* w2   = (const float*)d_in[21];
    const float* b2   = (const float*)d_in[22];
    const float* g2   = (const float*)d_in[23];
    const float* be2  = (const float*)d_in[24];
    const float* gf   = (const float*)d_in[25];
    const float* bfin = (const float*)d_in[26];
    const float* pw   = (const float*)d_in[27];
    const float* pb   = (const float*)d_in[28];
    float* outp = (float*)d_out;

    float* ws = (float*)d_ws;
    float* H   = ws;                 // 1024x512
    float* Y   = ws + 524288;        // 1024x512
    float* Qb  = ws + 1048576;       // 1024x512
    float* Kb  = ws + 1572864;       // 1024x512
    float* Vb  = ws + 2097152;       // 1024x512
    float* Ab  = ws + 2621440;       // 1024x512
    float* EMB = ws + 3145728;       // 1024x768
    float* FF  = ws + 3932160;       // 1024x2048
    float* KVC = ws + 6029312;       // 16*8*4096
    float* KVP = ws + 6553600;       // 16*8*4096
    float* KSC = ws + 7077888;       // 16*8*64
    float* KSP = ws + 7086080;       // 16*8*64  (end 7094272 floats = 28.4 MB)

    const dim3 blk(256);
    const dim3 g512(DM / 64, S_LEN / 64);      // N=512 GEMMs
    const dim3 g2048(DFF / 64, S_LEN / 64);    // N=2048 GEMM

    // embedding + input projection + positional encoding
    embed_kernel<<<S_LEN, blk, 0, stream>>>(x, e0, e1, e2, e3, e4, e5, EMB);
    gemm_kernel<<<g512, blk, 0, stream>>>(EMB, in_w, in_b, nullptr, H,
                                          S_LEN, DM, 768, ACT_NONE, 1);

    for (int l = 0; l < NLAYER; ++l) {
        const float* wq_l = wq + (size_t)l * DM * DM;  const float* bq_l = bq + l * DM;
        const float* wk_l = wk + (size_t)l * DM * DM;  const float* bk_l = bk + l * DM;
        const float* wv_l = wv + (size_t)l * DM * DM;  const float* bv_l = bv + l * DM;
        const float* wo_l = wo + (size_t)l * DM * DM;  const float* bo_l = bo + l * DM;
        const float* w1_l = w1 + (size_t)l * DM * DFF; const float* b1_l = b1 + l * DFF;
        const float* w2_l = w2 + (size_t)l * DFF * DM; const float* b2_l = b2 + l * DM;

        gemm_kernel<<<g512, blk, 0, stream>>>(H, wq_l, bq_l, nullptr, Qb,
                                              S_LEN, DM, DM, ACT_PHI, 0);
        gemm_kernel<<<g512, blk, 0, stream>>>(H, wk_l, bk_l, nullptr, Kb,
                                              S_LEN, DM, DM, ACT_PHI, 0);
        gemm_kernel<<<g512, blk, 0, stream>>>(H, wv_l, bv_l, nullptr, Vb,
                                              S_LEN, DM, DM, ACT_NONE, 0);

        chunk_stats_kernel<<<NCH * NH, blk, 0, stream>>>(Kb, Vb, KVC, KSC);
        prefix_kernel<<<NH, blk, 0, stream>>>(KVC, KSC, KVP, KSP);
        attn_out_kernel<<<NCH * NH, blk, 0, stream>>>(Qb, Kb, Vb, KVP, KSP, Ab);

        gemm_kernel<<<g512, blk, 0, stream>>>(Ab, wo_l, bo_l, H, Y,
                                              S_LEN, DM, DM, ACT_NONE, 0);
        ln_kernel<<<S_LEN, blk, 0, stream>>>(Y, g1 + l * DM, be1 + l * DM, H);

        gemm_kernel<<<g2048, blk, 0, stream>>>(H, w1_l, b1_l, nullptr, FF,
                                               S_LEN, DFF, DM, ACT_GELU, 0);
        gemm_kernel<<<g512, blk, 0, stream>>>(FF, w2_l, b2_l, H, Y,
                                              S_LEN, DM, DFF, ACT_NONE, 0);
        ln_kernel<<<S_LEN, blk, 0, stream>>>(Y, g2 + l * DM, be2 + l * DM, H);
    }

    // final norm -> d_out (f32 h), then emotion head reads it
    ln_kernel<<<S_LEN, blk, 0, stream>>>(H, gf, bfin, outp);
    proj_emo_kernel<<<8192 / 256, blk, 0, stream>>>(outp, pw, pb, outp + 524288);
}

// Round 3
// 3107.214 us; speedup vs baseline: 2.4119x; 2.4119x over previous
//
#include <hip/hip_runtime.h>
#include <hip/hip_bf16.h>
#include <math.h>

// ---------------------------------------------------------------------------
// TransformerModel: 12-layer causal linear-attention encoder.
// B=1, S=1024, D_MODEL=512, H=8, Dh=64, FF=2048. All tensors fp32 (x int32).
// Round 3: bf16 MFMA GEMMs (16x16x32), fused QKV, fp32 LN/attention.
// ---------------------------------------------------------------------------

#define S_LEN 1024
#define DM 512
#define NH 8
#define DH 64
#define DFF 2048
#define NLAYER 12
#define CHUNK 64
#define NCH (S_LEN / CHUNK)   // 16

#define ACT_NONE 0
#define ACT_PHI  1
#define ACT_GELU 2

typedef short s16x8 __attribute__((ext_vector_type(8)));
typedef short s16x4 __attribute__((ext_vector_type(4)));
typedef float f32x4 __attribute__((ext_vector_type(4)));
typedef int   i32x4 __attribute__((ext_vector_type(4)));

__device__ __forceinline__ short f2bf(float x) {
    __hip_bfloat16 h = __float2bfloat16(x);
    return *reinterpret_cast<short*>(&h);
}

// ---------------- embedding gather (writes bf16) ----------------
__global__ __launch_bounds__(256) void embed_kernel(
    const int* __restrict__ x,
    const float* __restrict__ t0, const float* __restrict__ t1,
    const float* __restrict__ t2, const float* __restrict__ t3,
    const float* __restrict__ t4, const float* __restrict__ t5,
    short* __restrict__ EMBb)
{
    int s = blockIdx.x;
    __shared__ int xi[6];
    if (threadIdx.x < 6) xi[threadIdx.x] = x[s * 6 + threadIdx.x];
    __syncthreads();
    for (int j = threadIdx.x; j < 768; j += 256) {
        int i, off, width; const float* t; float sc;
        if (j < 32)       { i = 0; off = 0;   t = t0; sc = 5.656854249f;  width = 32;  }
        else if (j < 160) { i = 1; off = 32;  t = t1; sc = 11.3137085f;   width = 128; }
        else if (j < 416) { i = 2; off = 160; t = t2; sc = 16.0f;         width = 256; }
        else if (j < 672) { i = 3; off = 416; t = t3; sc = 16.0f;         width = 256; }
        else if (j < 704) { i = 4; off = 672; t = t4; sc = 5.656854249f;  width = 32;  }
        else              { i = 5; off = 704; t = t5; sc = 8.0f;          width = 64;  }
        EMBb[s * 768 + j] = f2bf(t[xi[i] * width + (j - off)] * sc);
    }
}

// ---------------- MFMA GEMM core: one 64x64 output tile ----------------
// Abf: bf16 [M,K] activations; W: fp32 [K,N] weights (inline-converted).
// LDS rows padded to 40 shorts (80 B): 16B-aligned b128, 2-way bank max.
// Fragment layouts (guide, m89/m91-verified):
//   A: lane -> A[m=lane&15][k=(lane>>4)*8+j]
//   B: lane -> B[k=(lane>>4)*8+j][n=lane&15]
//   C/D: lane,reg -> C[row=(lane>>4)*4+reg][col=lane&15]
__device__ __forceinline__ void gemm_mfma_core(
    const short* __restrict__ Abf, const float* __restrict__ W,
    int K, int N, int row0, int col0,
    short (*As)[40], short (*Bs)[40], f32x4 acc[4])
{
    const int tid = threadIdx.x;
    const int lane = tid & 63, w = tid >> 6;
    const int q = lane >> 4, l15 = lane & 15;
    const int ar = tid >> 2, ac = (tid & 3) * 8;       // A staging: row, k-offset
    const int bn = tid & 63, bk0 = (tid >> 6) * 4;     // B staging: col(n), k-strip

    for (int k0 = 0; k0 < K; k0 += 32) {
        if (k0) __syncthreads();
        // stage A tile 64x32 (bf16 direct, 16B vector)
        i32x4 av = *(const i32x4*)(Abf + (size_t)(row0 + ar) * K + k0 + ac);
        *(i32x4*)&As[ar][ac] = av;
        // stage B tile 32x64 transposed -> Bs[n][k], fp32->bf16 inline
        #pragma unroll
        for (int jj = 0; jj < 2; ++jj) {
            int kb = jj * 16 + bk0;
            const float* wp = W + (size_t)(k0 + kb) * N + col0 + bn;
            s16x4 bw;
            bw.x = f2bf(wp[0]);
            bw.y = f2bf(wp[(size_t)N]);
            bw.z = f2bf(wp[(size_t)2 * N]);
            bw.w = f2bf(wp[(size_t)3 * N]);
            *(s16x4*)&Bs[bn][kb] = bw;
        }
        __syncthreads();
        s16x8 af = *(const s16x8*)&As[w * 16 + l15][q * 8];
        #pragma unroll
        for (int tb = 0; tb < 4; ++tb) {
            s16x8 bfv = *(const s16x8*)&Bs[tb * 16 + l15][q * 8];
            acc[tb] = __builtin_amdgcn_mfma_f32_16x16x32_bf16(af, bfv, acc[tb], 0, 0, 0);
        }
    }
}

__device__ __forceinline__ float apply_act(float v, int act) {
    if (act == ACT_PHI)       return (v > 0.0f) ? (v + 1.0f) : expf(v);
    else if (act == ACT_GELU) return 0.5f * v * (1.0f + erff(v * 0.70710678118654752f));
    return v;
}

// ---------------- generic MFMA GEMM kernel ----------------
__global__ __launch_bounds__(256) void gemm_mfma(
    const short* __restrict__ Abf, const float* __restrict__ W,
    const float* __restrict__ bias, const float* __restrict__ resid,
    float* __restrict__ Cf, short* __restrict__ Cbf,
    int N, int K, int act, int add_pe)
{
    __shared__ short As[64][40];
    __shared__ short Bs[64][40];
    const int row0 = blockIdx.y * 64, col0 = blockIdx.x * 64;
    const int lane = threadIdx.x & 63, w = threadIdx.x >> 6;
    const int q = lane >> 4, l15 = lane & 15;
    f32x4 acc[4] = {};
    gemm_mfma_core(Abf, W, K, N, row0, col0, As, Bs, acc);

    const int crow = row0 + w * 16 + q * 4;
    #pragma unroll
    for (int tb = 0; tb < 4; ++tb) {
        int c = col0 + tb * 16 + l15;
        float bia = bias[c];
        #pragma unroll
        for (int rg = 0; rg < 4; ++rg) {
            int r = crow + rg;
            float v = apply_act(acc[tb][rg] + bia, act);
            if (resid) v += resid[(size_t)r * N + c];
            if (add_pe) {
                float freq = expf((float)(c & ~1) * (-9.210340371976184f / 512.0f));
                float ang = (float)r * freq;
                v += (c & 1) ? cosf(ang) : sinf(ang);
            }
            if (Cf)  Cf[(size_t)r * N + c] = v;
            if (Cbf) Cbf[(size_t)r * N + c] = f2bf(v);
        }
    }
}

// ---------------- fused QKV GEMM: grid.x = 24 (8 per matrix) ----------------
__global__ __launch_bounds__(256) void qkv_mfma(
    const short* __restrict__ Hb,
    const float* __restrict__ wq, const float* __restrict__ wk, const float* __restrict__ wv,
    const float* __restrict__ bq, const float* __restrict__ bk, const float* __restrict__ bv,
    float* __restrict__ Qb, float* __restrict__ Kb, float* __restrict__ Vb)
{
    __shared__ short As[64][40];
    __shared__ short Bs[64][40];
    const int sel = blockIdx.x >> 3;
    const int col0 = (blockIdx.x & 7) * 64;
    const int row0 = blockIdx.y * 64;
    const float* W    = (sel == 0) ? wq : (sel == 1) ? wk : wv;
    const float* bias = (sel == 0) ? bq : (sel == 1) ? bk : bv;
    float* C          = (sel == 0) ? Qb : (sel == 1) ? Kb : Vb;
    const int act = (sel < 2) ? ACT_PHI : ACT_NONE;

    const int lane = threadIdx.x & 63, w = threadIdx.x >> 6;
    const int q = lane >> 4, l15 = lane & 15;
    f32x4 acc[4] = {};
    gemm_mfma_core(Hb, W, DM, DM, row0, col0, As, Bs, acc);

    const int crow = row0 + w * 16 + q * 4;
    #pragma unroll
    for (int tb = 0; tb < 4; ++tb) {
        int c = col0 + tb * 16 + l15;
        float bia = bias[c];
        #pragma unroll
        for (int rg = 0; rg < 4; ++rg) {
            int r = crow + rg;
            C[(size_t)r * DM + c] = apply_act(acc[tb][rg] + bia, act);
        }
    }
}

// ---------------- chunk stats: per (head, chunk) KV_c = K_c^T V_c, ksum_c ----------------
__global__ __launch_bounds__(256) void chunk_stats_kernel(
    const float* __restrict__ Kb, const float* __restrict__ Vb,
    float* __restrict__ KVC, float* __restrict__ KSC)
{
    const int h = blockIdx.x >> 4, c = blockIdx.x & 15;
    const int tid = threadIdx.x;
    __shared__ float Ks[CHUNK][64];
    __shared__ float Vs[CHUNK][64];
    for (int i = tid; i < CHUNK * 64; i += 256) {
        int r = i >> 6, cc = i & 63;
        Ks[r][cc] = Kb[(size_t)(c * CHUNK + r) * DM + h * 64 + cc];
        Vs[r][cc] = Vb[(size_t)(c * CHUNK + r) * DM + h * 64 + cc];
    }
    __syncthreads();
    const int e = tid & 63, dg = tid >> 6;
    float acc[16] = {};
    for (int t = 0; t < CHUNK; ++t) {
        float vv = Vs[t][e];
        #pragma unroll
        for (int i = 0; i < 16; ++i) acc[i] += Ks[t][dg * 16 + i] * vv;
    }
    float* out = KVC + ((size_t)(c * NH + h)) * 4096;
    #pragma unroll
    for (int i = 0; i < 16; ++i) out[(dg * 16 + i) * 64 + e] = acc[i];
    if (tid < 64) {
        float s = 0.0f;
        for (int t = 0; t < CHUNK; ++t) s += Ks[t][tid];
        KSC[(size_t)(c * NH + h) * 64 + tid] = s;
    }
}

// ---------------- exclusive prefix over chunks ----------------
__global__ __launch_bounds__(256) void prefix_kernel(
    const float* __restrict__ KVC, const float* __restrict__ KSC,
    float* __restrict__ KVP, float* __restrict__ KSP)
{
    const int h = blockIdx.x;
    const int tid = threadIdx.x;
    for (int i = tid; i < 4096; i += 256) {
        float run = 0.0f;
        for (int c = 0; c < NCH; ++c) {
            size_t idx = ((size_t)(c * NH + h)) * 4096 + i;
            KVP[idx] = run;
            run += KVC[idx];
        }
    }
    if (tid < 64) {
        float run = 0.0f;
        for (int c = 0; c < NCH; ++c) {
            size_t idx = (size_t)(c * NH + h) * 64 + tid;
            KSP[idx] = run;
            run += KSC[idx];
        }
    }
}

// ---------------- attention output per (head, chunk), writes bf16 ----------------
__global__ __launch_bounds__(256) void attn_out_kernel(
    const float* __restrict__ Qb, const float* __restrict__ Kb,
    const float* __restrict__ Vb, const float* __restrict__ KVP,
    const float* __restrict__ KSP, short* __restrict__ Ab)
{
    const int h = blockIdx.x >> 4, c = blockIdx.x & 15;
    const int tid = threadIdx.x;
    __shared__ float Qs[CHUNK][65];
    __shared__ float Ks[CHUNK][65];
    __shared__ float Vs[CHUNK][65];
    __shared__ float KSs[64];
    for (int i = tid; i < CHUNK * 64; i += 256) {
        int r = i >> 6, cc = i & 63;
        size_t g = (size_t)(c * CHUNK + r) * DM + h * 64 + cc;
        Qs[r][cc] = Qb[g];
        Ks[r][cc] = Kb[g];
        Vs[r][cc] = Vb[g];
    }
    if (tid < 64) KSs[tid] = KSP[(size_t)(c * NH + h) * 64 + tid];
    __syncthreads();

    const int s = tid >> 2;
    const int e0 = (tid & 3) * 16;
    float acc[16] = {};
    float den = 0.0f;

    const float* kvp = KVP + ((size_t)(c * NH + h)) * 4096;
    for (int d = 0; d < 64; ++d) {
        float qd = Qs[s][d];
        den += qd * KSs[d];
        const float* row = kvp + d * 64 + e0;
        #pragma unroll
        for (int j = 0; j < 16; ++j) acc[j] += qd * row[j];
    }
    for (int t = 0; t <= s; ++t) {
        float sc = 0.0f;
        #pragma unroll
        for (int d = 0; d < 64; ++d) sc += Qs[s][d] * Ks[t][d];
        den += sc;
        #pragma unroll
        for (int j = 0; j < 16; ++j) acc[j] += sc * Vs[t][e0 + j];
    }
    float z = 1.0f / (den + 1e-6f);
    short* out = Ab + (size_t)(c * CHUNK + s) * DM + h * 64 + e0;
    #pragma unroll
    for (int j = 0; j < 16; ++j) out[j] = f2bf(acc[j] * z);
}

// ---------------- layernorm (fp32 out + optional bf16 mirror) ----------------
__device__ __forceinline__ float block_reduce_sum(float v, float* smem)
{
    #pragma unroll
    for (int o = 32; o > 0; o >>= 1) v += __shfl_down(v, o, 64);
    int w = threadIdx.x >> 6;
    if ((threadIdx.x & 63) == 0) smem[w] = v;
    __syncthreads();
    v = smem[0] + smem[1] + smem[2] + smem[3];
    __syncthreads();
    return v;
}

__global__ __launch_bounds__(256) void ln_kernel(
    const float* __restrict__ X, const float* __restrict__ g,
    const float* __restrict__ b, float* __restrict__ O, short* __restrict__ Ob)
{
    __shared__ float red[4];
    const int row = blockIdx.x;
    const float* x = X + (size_t)row * DM;
    const int t = threadIdx.x;
    float v0 = x[t], v1 = x[t + 256];
    float mean = block_reduce_sum(v0 + v1, red) * (1.0f / 512.0f);
    float d0 = v0 - mean, d1 = v1 - mean;
    float var = block_reduce_sum(d0 * d0 + d1 * d1, red) * (1.0f / 512.0f);
    float rs = 1.0f / sqrtf(var + 1e-5f);
    float o0 = d0 * rs * g[t] + b[t];
    float o1 = d1 * rs * g[t + 256] + b[t + 256];
    O[(size_t)row * DM + t]       = o0;
    O[(size_t)row * DM + t + 256] = o1;
    if (Ob) {
        Ob[(size_t)row * DM + t]       = f2bf(o0);
        Ob[(size_t)row * DM + t + 256] = f2bf(o1);
    }
}

// ---------------- emotion head: [1024,512] @ [512,8] + b ----------------
__global__ __launch_bounds__(256) void proj_emo_kernel(
    const float* __restrict__ HF, const float* __restrict__ pw,
    const float* __restrict__ pb, float* __restrict__ out)
{
    int idx = blockIdx.x * 256 + threadIdx.x;
    int r = idx >> 3, e = idx & 7;
    float acc = pb[e];
    const float* h = HF + (size_t)r * DM;
    for (int d = 0; d < DM; ++d) acc += h[d] * pw[d * 8 + e];
    out[idx] = acc;
}

// ---------------------------------------------------------------------------
extern "C" void kernel_launch(void* const* d_in, const int* in_sizes, int n_in,
                              void* d_out, int out_size, void* d_ws, size_t ws_size,
                              hipStream_t stream)
{
    const int*   x    = (const int*)d_in[0];
    const float* e0   = (const float*)d_in[1];
    const float* e1   = (const float*)d_in[2];
    const float* e2   = (const float*)d_in[3];
    const float* e3   = (const float*)d_in[4];
    const float* e4   = (const float*)d_in[5];
    const float* e5   = (const float*)d_in[6];
    const float* in_w = (const float*)d_in[7];
    const float* in_b = (const float*)d_in[8];
    const float* wq   = (const float*)d_in[9];
    const float* bq   = (const float*)d_in[10];
    const float* wk   = (const float*)d_in[11];
    const float* bk   = (const float*)d_in[12];
    const float* wv   = (const float*)d_in[13];
    const float* bv   = (const float*)d_in[14];
    const float* wo   = (const float*)d_in[15];
    const float* bo   = (const float*)d_in[16];
    const float* g1   = (const float*)d_in[17];
    const float* be1  = (const float*)d_in[18];
    const float* w1   = (const float*)d_in[19];
    const float* b1   = (const float*)d_in[20];
    const float* w2   = (const float*)d_in[21];
    const float* b2   = (const float*)d_in[22];
    const float* g2   = (const float*)d_in[23];
    const float* be2  = (const float*)d_in[24];
    const float* gf   = (const float*)d_in[25];
    const float* bfin = (const float*)d_in[26];
    const float* pw   = (const float*)d_in[27];
    const float* pb   = (const float*)d_in[28];
    float* outp = (float*)d_out;

    // workspace layout (fp32 words)
    float* ws = (float*)d_ws;
    float* H    = ws;                  // 1024x512 f32
    float* Y    = ws + 524288;         // 1024x512 f32
    float* Qb   = ws + 1048576;        // 1024x512 f32
    float* Kb   = ws + 1572864;        // 1024x512 f32
    float* Vb   = ws + 2097152;        // 1024x512 f32
    float* KVC  = ws + 2621440;        // 16*8*4096 f32
    float* KVP  = ws + 3145728;        // 16*8*4096 f32
    float* KSC  = ws + 3670016;        // 16*8*64 f32
    float* KSP  = ws + 3678208;        // 16*8*64 f32
    short* Hb   = (short*)(ws + 3686400);   // 1024x512 bf16
    short* EMBb = (short*)(ws + 3948544);   // 1024x768 bf16
    short* Ab   = (short*)(ws + 4341760);   // 1024x512 bf16
    short* FFb  = (short*)(ws + 4603904);   // 1024x2048 bf16 (end ~22.2 MB)

    const dim3 blk(256);
    const dim3 g512(8, 16);        // N=512 MFMA GEMMs
    const dim3 g2048(32, 16);      // N=2048 MFMA GEMM
    const dim3 gqkv(24, 16);       // fused QKV

    embed_kernel<<<S_LEN, blk, 0, stream>>>(x, e0, e1, e2, e3, e4, e5, EMBb);
    // in-proj: EMBb @ in_w + in_b + PE -> H (f32) and Hb (bf16)
    gemm_mfma<<<g512, blk, 0, stream>>>(EMBb, in_w, in_b, nullptr, H, Hb,
                                        DM, 768, ACT_NONE, 1);

    for (int l = 0; l < NLAYER; ++l) {
        const float* wq_l = wq + (size_t)l * DM * DM;  const float* bq_l = bq + l * DM;
        const float* wk_l = wk + (size_t)l * DM * DM;  const float* bk_l = bk + l * DM;
        const float* wv_l = wv + (size_t)l * DM * DM;  const float* bv_l = bv + l * DM;
        const float* wo_l = wo + (size_t)l * DM * DM;  const float* bo_l = bo + l * DM;
        const float* w1_l = w1 + (size_t)l * DM * DFF; const float* b1_l = b1 + l * DFF;
        const float* w2_l = w2 + (size_t)l * DFF * DM; const float* b2_l = b2 + l * DM;

        qkv_mfma<<<gqkv, blk, 0, stream>>>(Hb, wq_l, wk_l, wv_l, bq_l, bk_l, bv_l,
                                           Qb, Kb, Vb);

        chunk_stats_kernel<<<NCH * NH, blk, 0, stream>>>(Kb, Vb, KVC, KSC);
        prefix_kernel<<<NH, blk, 0, stream>>>(KVC, KSC, KVP, KSP);
        attn_out_kernel<<<NCH * NH, blk, 0, stream>>>(Qb, Kb, Vb, KVP, KSP, Ab);

        // wo: Ab @ wo + bo + H -> Y (f32)
        gemm_mfma<<<g512, blk, 0, stream>>>(Ab, wo_l, bo_l, H, Y, nullptr,
                                            DM, DM, ACT_NONE, 0);
        ln_kernel<<<S_LEN, blk, 0, stream>>>(Y, g1 + l * DM, be1 + l * DM, H, Hb);

        // ffn1: Hb @ w1 + b1, GELU -> FFb (bf16 only)
        gemm_mfma<<<g2048, blk, 0, stream>>>(Hb, w1_l, b1_l, nullptr, nullptr, FFb,
                                             DFF, DM, ACT_GELU, 0);
        // ffn2: FFb @ w2 + b2 + H -> Y (f32)
        gemm_mfma<<<g512, blk, 0, stream>>>(FFb, w2_l, b2_l, H, Y, nullptr,
                                            DM, DFF, ACT_NONE, 0);
        ln_kernel<<<S_LEN, blk, 0, stream>>>(Y, g2 + l * DM, be2 + l * DM, H, Hb);
    }

    ln_kernel<<<S_LEN, blk, 0, stream>>>(H, gf, bfin, outp, nullptr);
    proj_emo_kernel<<<8192 / 256, blk, 0, stream>>>(outp, pw, pb, outp + 524288);
}

// Round 4
// 2961.560 us; speedup vs baseline: 2.5306x; 1.0492x over previous
//
#include <hip/hip_runtime.h>
#include <hip/hip_bf16.h>
#include <math.h>

// ---------------------------------------------------------------------------
// TransformerModel: 12-layer causal linear-attention encoder.
// B=1, S=1024, D_MODEL=512, H=8, Dh=64, FF=2048. All tensors fp32 (x int32).
// Round 4: direct-from-global MFMA GEMMs (no LDS, no barriers in K-loop),
// weights pre-transposed+converted to bf16 [N][K] arena once per launch.
// ---------------------------------------------------------------------------

#define S_LEN 1024
#define DM 512
#define NH 8
#define DH 64
#define DFF 2048
#define NLAYER 12
#define CHUNK 64
#define NCH (S_LEN / CHUNK)   // 16

#define ACT_NONE 0
#define ACT_PHI  1
#define ACT_GELU 2

typedef short s16x8 __attribute__((ext_vector_type(8)));
typedef float f32x4 __attribute__((ext_vector_type(4)));

__device__ __forceinline__ short f2bf(float x) {
    __hip_bfloat16 h = __float2bfloat16(x);
    return *reinterpret_cast<short*>(&h);
}

// ---------------- embedding gather (writes bf16) ----------------
__global__ __launch_bounds__(256) void embed_kernel(
    const int* __restrict__ x,
    const float* __restrict__ t0, const float* __restrict__ t1,
    const float* __restrict__ t2, const float* __restrict__ t3,
    const float* __restrict__ t4, const float* __restrict__ t5,
    short* __restrict__ EMBb)
{
    int s = blockIdx.x;
    __shared__ int xi[6];
    if (threadIdx.x < 6) xi[threadIdx.x] = x[s * 6 + threadIdx.x];
    __syncthreads();
    for (int j = threadIdx.x; j < 768; j += 256) {
        int i, off, width; const float* t; float sc;
        if (j < 32)       { i = 0; off = 0;   t = t0; sc = 5.656854249f;  width = 32;  }
        else if (j < 160) { i = 1; off = 32;  t = t1; sc = 11.3137085f;   width = 128; }
        else if (j < 416) { i = 2; off = 160; t = t2; sc = 16.0f;         width = 256; }
        else if (j < 672) { i = 3; off = 416; t = t3; sc = 16.0f;         width = 256; }
        else if (j < 704) { i = 4; off = 672; t = t4; sc = 5.656854249f;  width = 32;  }
        else              { i = 5; off = 704; t = t5; sc = 8.0f;          width = 64;  }
        EMBb[s * 768 + j] = f2bf(t[xi[i] * width + (j - off)] * sc);
    }
}

// ---------------- weight transpose+convert: f32 [B][K][N] -> bf16 [B][N][K] ----
// 64x64 tiles via LDS; pad 66 shorts (33 dwords) -> conflict-free transpose.
__global__ __launch_bounds__(256) void transpose_w(
    const float* __restrict__ in, short* __restrict__ out, int K, int N)
{
    __shared__ short t[64][66];
    const int b = blockIdx.z;
    const int n0 = blockIdx.x * 64, k0 = blockIdx.y * 64;
    const float* ip = in + (size_t)b * K * N;
    short* op = out + (size_t)b * K * N;
    const int c = threadIdx.x & 63, r0 = (threadIdx.x >> 6) * 16;
    #pragma unroll
    for (int i = 0; i < 16; ++i)
        t[c][r0 + i] = f2bf(ip[(size_t)(k0 + r0 + i) * N + n0 + c]);
    __syncthreads();
    #pragma unroll
    for (int i = 0; i < 16; ++i)
        op[(size_t)(n0 + r0 + i) * K + k0 + c] = t[r0 + i][c];
}

// ---------------- activation ----------------
__device__ __forceinline__ float apply_act(float v, int act) {
    if (act == ACT_PHI)       return (v > 0.0f) ? (v + 1.0f) : expf(v);
    else if (act == ACT_GELU) return 0.5f * v * (1.0f + erff(v * 0.70710678118654752f));
    return v;
}

// ---------------- direct-wave MFMA GEMM: 1 wave = one 64x64 tile ----------------
// A: bf16 [M,K] row-major. BT: bf16 [N,K] row-major (W^T). No LDS, no barriers.
// Fragments (guide m89/m91): A: lane->A[m=l15][k=q*8+j]; B: lane->B[k=q*8+j][n=l15]
//   (b-frag fed from BT[n][k..k+8] contiguous); C/D: row=q*4+reg, col=l15.
__device__ __forceinline__ void gemm_dw_core(
    const short* __restrict__ A, const short* __restrict__ BT,
    int K, int row0, int col0, int q, int l15, f32x4 acc[4][4])
{
    const short* ap = A  + (size_t)(row0 + l15) * K + q * 8;
    const short* bp = BT + (size_t)(col0 + l15) * K + q * 8;
    #pragma unroll 2
    for (int k0 = 0; k0 < K; k0 += 32) {
        s16x8 af[4], bfr[4];
        #pragma unroll
        for (int i = 0; i < 4; ++i)
            af[i] = *(const s16x8*)(ap + (size_t)i * 16 * K + k0);
        #pragma unroll
        for (int i = 0; i < 4; ++i)
            bfr[i] = *(const s16x8*)(bp + (size_t)i * 16 * K + k0);
        #pragma unroll
        for (int mi = 0; mi < 4; ++mi)
            #pragma unroll
            for (int ni = 0; ni < 4; ++ni)
                acc[mi][ni] = __builtin_amdgcn_mfma_f32_16x16x32_bf16(
                    af[mi], bfr[ni], acc[mi][ni], 0, 0, 0);
    }
}

__global__ __launch_bounds__(64) void gemm_dw(
    const short* __restrict__ A, const short* __restrict__ BT,
    const float* __restrict__ bias, const float* __restrict__ resid,
    float* __restrict__ Cf, short* __restrict__ Cbf,
    int N, int K, int act, int add_pe)
{
    const int row0 = blockIdx.y * 64, col0 = blockIdx.x * 64;
    const int lane = threadIdx.x, q = lane >> 4, l15 = lane & 15;
    f32x4 acc[4][4] = {};
    gemm_dw_core(A, BT, K, row0, col0, q, l15, acc);
    #pragma unroll
    for (int ni = 0; ni < 4; ++ni) {
        int c = col0 + ni * 16 + l15;
        float bia = bias[c];
        #pragma unroll
        for (int mi = 0; mi < 4; ++mi) {
            #pragma unroll
            for (int rg = 0; rg < 4; ++rg) {
                int r = row0 + mi * 16 + q * 4 + rg;
                float v = apply_act(acc[mi][ni][rg] + bia, act);
                if (resid) v += resid[(size_t)r * N + c];
                if (add_pe) {
                    float freq = expf((float)(c & ~1) * (-9.210340371976184f / 512.0f));
                    float ang = (float)r * freq;
                    v += (c & 1) ? cosf(ang) : sinf(ang);
                }
                if (Cf)  Cf[(size_t)r * N + c] = v;
                if (Cbf) Cbf[(size_t)r * N + c] = f2bf(v);
            }
        }
    }
}

// ---------------- fused QKV (grid.x = 24: 8 col-tiles per matrix) ----------------
__global__ __launch_bounds__(64) void qkv_dw(
    const short* __restrict__ Hb,
    const short* __restrict__ qT, const short* __restrict__ kT, const short* __restrict__ vT,
    const float* __restrict__ bq, const float* __restrict__ bk, const float* __restrict__ bv,
    float* __restrict__ Qb, float* __restrict__ Kb, float* __restrict__ Vb)
{
    const int sel = blockIdx.x >> 3;
    const int col0 = (blockIdx.x & 7) * 64;
    const int row0 = blockIdx.y * 64;
    const short* BT   = (sel == 0) ? qT : (sel == 1) ? kT : vT;
    const float* bias = (sel == 0) ? bq : (sel == 1) ? bk : bv;
    float* C          = (sel == 0) ? Qb : (sel == 1) ? Kb : Vb;
    const int act = (sel < 2) ? ACT_PHI : ACT_NONE;

    const int lane = threadIdx.x, q = lane >> 4, l15 = lane & 15;
    f32x4 acc[4][4] = {};
    gemm_dw_core(Hb, BT, DM, row0, col0, q, l15, acc);
    #pragma unroll
    for (int ni = 0; ni < 4; ++ni) {
        int c = col0 + ni * 16 + l15;
        float bia = bias[c];
        #pragma unroll
        for (int mi = 0; mi < 4; ++mi) {
            #pragma unroll
            for (int rg = 0; rg < 4; ++rg) {
                int r = row0 + mi * 16 + q * 4 + rg;
                C[(size_t)r * DM + c] = apply_act(acc[mi][ni][rg] + bia, act);
            }
        }
    }
}

// ---------------- chunk stats: per (head, chunk) KV_c = K_c^T V_c, ksum_c ----------------
__global__ __launch_bounds__(256) void chunk_stats_kernel(
    const float* __restrict__ Kb, const float* __restrict__ Vb,
    float* __restrict__ KVC, float* __restrict__ KSC)
{
    const int h = blockIdx.x >> 4, c = blockIdx.x & 15;
    const int tid = threadIdx.x;
    __shared__ float Ks[CHUNK][64];
    __shared__ float Vs[CHUNK][64];
    for (int i = tid; i < CHUNK * 64; i += 256) {
        int r = i >> 6, cc = i & 63;
        Ks[r][cc] = Kb[(size_t)(c * CHUNK + r) * DM + h * 64 + cc];
        Vs[r][cc] = Vb[(size_t)(c * CHUNK + r) * DM + h * 64 + cc];
    }
    __syncthreads();
    const int e = tid & 63, dg = tid >> 6;
    float acc[16] = {};
    for (int t = 0; t < CHUNK; ++t) {
        float vv = Vs[t][e];
        #pragma unroll
        for (int i = 0; i < 16; ++i) acc[i] += Ks[t][dg * 16 + i] * vv;
    }
    float* out = KVC + ((size_t)(c * NH + h)) * 4096;
    #pragma unroll
    for (int i = 0; i < 16; ++i) out[(dg * 16 + i) * 64 + e] = acc[i];
    if (tid < 64) {
        float s = 0.0f;
        for (int t = 0; t < CHUNK; ++t) s += Ks[t][tid];
        KSC[(size_t)(c * NH + h) * 64 + tid] = s;
    }
}

// ---------------- exclusive prefix over chunks ----------------
__global__ __launch_bounds__(256) void prefix_kernel(
    const float* __restrict__ KVC, const float* __restrict__ KSC,
    float* __restrict__ KVP, float* __restrict__ KSP)
{
    const int h = blockIdx.x;
    const int tid = threadIdx.x;
    for (int i = tid; i < 4096; i += 256) {
        float run = 0.0f;
        for (int c = 0; c < NCH; ++c) {
            size_t idx = ((size_t)(c * NH + h)) * 4096 + i;
            KVP[idx] = run;
            run += KVC[idx];
        }
    }
    if (tid < 64) {
        float run = 0.0f;
        for (int c = 0; c < NCH; ++c) {
            size_t idx = (size_t)(c * NH + h) * 64 + tid;
            KSP[idx] = run;
            run += KSC[idx];
        }
    }
}

// ---------------- attention output per (head, chunk), writes bf16 ----------------
__global__ __launch_bounds__(256) void attn_out_kernel(
    const float* __restrict__ Qb, const float* __restrict__ Kb,
    const float* __restrict__ Vb, const float* __restrict__ KVP,
    const float* __restrict__ KSP, short* __restrict__ Ab)
{
    const int h = blockIdx.x >> 4, c = blockIdx.x & 15;
    const int tid = threadIdx.x;
    __shared__ float Qs[CHUNK][65];
    __shared__ float Ks[CHUNK][65];
    __shared__ float Vs[CHUNK][65];
    __shared__ float KSs[64];
    for (int i = tid; i < CHUNK * 64; i += 256) {
        int r = i >> 6, cc = i & 63;
        size_t g = (size_t)(c * CHUNK + r) * DM + h * 64 + cc;
        Qs[r][cc] = Qb[g];
        Ks[r][cc] = Kb[g];
        Vs[r][cc] = Vb[g];
    }
    if (tid < 64) KSs[tid] = KSP[(size_t)(c * NH + h) * 64 + tid];
    __syncthreads();

    const int s = tid >> 2;
    const int e0 = (tid & 3) * 16;
    float acc[16] = {};
    float den = 0.0f;

    const float* kvp = KVP + ((size_t)(c * NH + h)) * 4096;
    for (int d = 0; d < 64; ++d) {
        float qd = Qs[s][d];
        den += qd * KSs[d];
        const float* row = kvp + d * 64 + e0;
        #pragma unroll
        for (int j = 0; j < 16; ++j) acc[j] += qd * row[j];
    }
    for (int t = 0; t <= s; ++t) {
        float sc = 0.0f;
        #pragma unroll
        for (int d = 0; d < 64; ++d) sc += Qs[s][d] * Ks[t][d];
        den += sc;
        #pragma unroll
        for (int j = 0; j < 16; ++j) acc[j] += sc * Vs[t][e0 + j];
    }
    float z = 1.0f / (den + 1e-6f);
    short* out = Ab + (size_t)(c * CHUNK + s) * DM + h * 64 + e0;
    #pragma unroll
    for (int j = 0; j < 16; ++j) out[j] = f2bf(acc[j] * z);
}

// ---------------- layernorm (fp32 out + optional bf16 mirror) ----------------
__device__ __forceinline__ float block_reduce_sum(float v, float* smem)
{
    #pragma unroll
    for (int o = 32; o > 0; o >>= 1) v += __shfl_down(v, o, 64);
    int w = threadIdx.x >> 6;
    if ((threadIdx.x & 63) == 0) smem[w] = v;
    __syncthreads();
    v = smem[0] + smem[1] + smem[2] + smem[3];
    __syncthreads();
    return v;
}

__global__ __launch_bounds__(256) void ln_kernel(
    const float* __restrict__ X, const float* __restrict__ g,
    const float* __restrict__ b, float* __restrict__ O, short* __restrict__ Ob)
{
    __shared__ float red[4];
    const int row = blockIdx.x;
    const float* x = X + (size_t)row * DM;
    const int t = threadIdx.x;
    float v0 = x[t], v1 = x[t + 256];
    float mean = block_reduce_sum(v0 + v1, red) * (1.0f / 512.0f);
    float d0 = v0 - mean, d1 = v1 - mean;
    float var = block_reduce_sum(d0 * d0 + d1 * d1, red) * (1.0f / 512.0f);
    float rs = 1.0f / sqrtf(var + 1e-5f);
    float o0 = d0 * rs * g[t] + b[t];
    float o1 = d1 * rs * g[t + 256] + b[t + 256];
    O[(size_t)row * DM + t]       = o0;
    O[(size_t)row * DM + t + 256] = o1;
    if (Ob) {
        Ob[(size_t)row * DM + t]       = f2bf(o0);
        Ob[(size_t)row * DM + t + 256] = f2bf(o1);
    }
}

// ---------------- emotion head: [1024,512] @ [512,8] + b ----------------
__global__ __launch_bounds__(256) void proj_emo_kernel(
    const float* __restrict__ HF, const float* __restrict__ pw,
    const float* __restrict__ pb, float* __restrict__ out)
{
    int idx = blockIdx.x * 256 + threadIdx.x;
    int r = idx >> 3, e = idx & 7;
    float acc = pb[e];
    const float* h = HF + (size_t)r * DM;
    for (int d = 0; d < DM; ++d) acc += h[d] * pw[d * 8 + e];
    out[idx] = acc;
}

// ---------------------------------------------------------------------------
extern "C" void kernel_launch(void* const* d_in, const int* in_sizes, int n_in,
                              void* d_out, int out_size, void* d_ws, size_t ws_size,
                              hipStream_t stream)
{
    const int*   x    = (const int*)d_in[0];
    const float* e0   = (const float*)d_in[1];
    const float* e1   = (const float*)d_in[2];
    const float* e2   = (const float*)d_in[3];
    const float* e3   = (const float*)d_in[4];
    const float* e4   = (const float*)d_in[5];
    const float* e5   = (const float*)d_in[6];
    const float* in_w = (const float*)d_in[7];
    const float* in_b = (const float*)d_in[8];
    const float* wq   = (const float*)d_in[9];
    const float* bq   = (const float*)d_in[10];
    const float* wk   = (const float*)d_in[11];
    const float* bk   = (const float*)d_in[12];
    const float* wv   = (const float*)d_in[13];
    const float* bv   = (const float*)d_in[14];
    const float* wo   = (const float*)d_in[15];
    const float* bo   = (const float*)d_in[16];
    const float* g1   = (const float*)d_in[17];
    const float* be1  = (const float*)d_in[18];
    const float* w1   = (const float*)d_in[19];
    const float* b1   = (const float*)d_in[20];
    const float* w2   = (const float*)d_in[21];
    const float* b2   = (const float*)d_in[22];
    const float* g2   = (const float*)d_in[23];
    const float* be2  = (const float*)d_in[24];
    const float* gf   = (const float*)d_in[25];
    const float* bfin = (const float*)d_in[26];
    const float* pw   = (const float*)d_in[27];
    const float* pb   = (const float*)d_in[28];
    float* outp = (float*)d_out;

    // ---- workspace layout ----
    float* ws = (float*)d_ws;
    float* H    = ws;                  // 1024x512 f32
    float* Y    = ws + 524288;
    float* Qb   = ws + 1048576;
    float* Kb   = ws + 1572864;
    float* Vb   = ws + 2097152;
    float* KVC  = ws + 2621440;        // 16*8*4096
    float* KVP  = ws + 3145728;
    float* KSC  = ws + 3670016;
    float* KSP  = ws + 3678208;        // f32 region ends at 3686400 floats
    short* sb   = (short*)(ws + 3686400);
    short* Hb   = sb;                  // 1024x512
    short* EMBb = sb + 524288;         // 1024x768
    short* Ab   = sb + 1310720;        // 1024x512
    short* FFb  = sb + 1835008;        // 1024x2048
    // bf16 W^T arena [N][K]
    short* inT  = sb + 3932160;        // [512][768]
    short* qT   = inT + 393216;        // [12][512][512]
    short* kT   = qT + 3145728;
    short* vT   = kT + 3145728;
    short* oT   = vT + 3145728;
    short* w1T  = oT + 3145728;        // [12][2048][512]
    short* w2T  = w1T + 12582912;      // [12][512][2048]  (arena end ~98.9 MB)

    const dim3 blk256(256), blk64(64);

    // ---- weight transpose+convert (7 dispatches) ----
    transpose_w<<<dim3(8, 12, 1),  blk256, 0, stream>>>(in_w, inT, 768, DM);
    transpose_w<<<dim3(8, 8, 12),  blk256, 0, stream>>>(wq, qT, DM, DM);
    transpose_w<<<dim3(8, 8, 12),  blk256, 0, stream>>>(wk, kT, DM, DM);
    transpose_w<<<dim3(8, 8, 12),  blk256, 0, stream>>>(wv, vT, DM, DM);
    transpose_w<<<dim3(8, 8, 12),  blk256, 0, stream>>>(wo, oT, DM, DM);
    transpose_w<<<dim3(32, 8, 12), blk256, 0, stream>>>(w1, w1T, DM, DFF);
    transpose_w<<<dim3(8, 32, 12), blk256, 0, stream>>>(w2, w2T, DFF, DM);

    embed_kernel<<<S_LEN, blk256, 0, stream>>>(x, e0, e1, e2, e3, e4, e5, EMBb);
    // in-proj: EMBb @ in_w + in_b + PE -> H (f32) and Hb (bf16)
    gemm_dw<<<dim3(8, 16), blk64, 0, stream>>>(EMBb, inT, in_b, nullptr, H, Hb,
                                               DM, 768, ACT_NONE, 1);

    for (int l = 0; l < NLAYER; ++l) {
        const short* qT_l = qT + (size_t)l * DM * DM;
        const short* kT_l = kT + (size_t)l * DM * DM;
        const short* vT_l = vT + (size_t)l * DM * DM;
        const short* oT_l = oT + (size_t)l * DM * DM;
        const short* w1T_l = w1T + (size_t)l * DM * DFF;
        const short* w2T_l = w2T + (size_t)l * DM * DFF;
        const float* bq_l = bq + l * DM;  const float* bk_l = bk + l * DM;
        const float* bv_l = bv + l * DM;  const float* bo_l = bo + l * DM;
        const float* b1_l = b1 + l * DFF; const float* b2_l = b2 + l * DM;

        qkv_dw<<<dim3(24, 16), blk64, 0, stream>>>(Hb, qT_l, kT_l, vT_l,
                                                   bq_l, bk_l, bv_l, Qb, Kb, Vb);

        chunk_stats_kernel<<<NCH * NH, blk256, 0, stream>>>(Kb, Vb, KVC, KSC);
        prefix_kernel<<<NH, blk256, 0, stream>>>(KVC, KSC, KVP, KSP);
        attn_out_kernel<<<NCH * NH, blk256, 0, stream>>>(Qb, Kb, Vb, KVP, KSP, Ab);

        // wo: Ab @ wo + bo + H -> Y (f32)
        gemm_dw<<<dim3(8, 16), blk64, 0, stream>>>(Ab, oT_l, bo_l, H, Y, nullptr,
                                                   DM, DM, ACT_NONE, 0);
        ln_kernel<<<S_LEN, blk256, 0, stream>>>(Y, g1 + l * DM, be1 + l * DM, H, Hb);

        // ffn1: Hb @ w1 + b1, GELU -> FFb (bf16)
        gemm_dw<<<dim3(32, 16), blk64, 0, stream>>>(Hb, w1T_l, b1_l, nullptr,
                                                    nullptr, FFb, DFF, DM, ACT_GELU, 0);
        // ffn2: FFb @ w2 + b2 + H -> Y (f32)
        gemm_dw<<<dim3(8, 16), blk64, 0, stream>>>(FFb, w2T_l, b2_l, H, Y, nullptr,
                                                   DM, DFF, ACT_NONE, 0);
        ln_kernel<<<S_LEN, blk256, 0, stream>>>(Y, g2 + l * DM, be2 + l * DM, H, Hb);
    }

    ln_kernel<<<S_LEN, blk256, 0, stream>>>(H, gf, bfin, outp, nullptr);
    proj_emo_kernel<<<8192 / 256, blk256, 0, stream>>>(outp, pw, pb, outp + 524288);
}

// Round 9
// 1809.450 us; speedup vs baseline: 4.1418x; 1.6367x over previous
//
#include <hip/hip_runtime.h>
#include <hip/hip_bf16.h>
#include <math.h>

// ---------------------------------------------------------------------------
// TransformerModel: 12-layer causal linear-attention encoder.
// B=1, S=1024, D_MODEL=512, H=8, Dh=64, FF=2048. All tensors fp32 (x int32).
// Round 9: de-risked bisection. R4's proven dataflow (no split-K, dedicated
// buffers, direct epilogues) + 32x32-per-wave MFMA GEMMs + inline-prefix
// attention. Weights pre-transposed to bf16 [N][K].
// ---------------------------------------------------------------------------

#define S_LEN 1024
#define DM 512
#define NH 8
#define DH 64
#define DFF 2048
#define NLAYER 12
#define CHUNK 64
#define NCH (S_LEN / CHUNK)   // 16

#define ACT_NONE 0
#define ACT_PHI  1
#define ACT_GELU 2

typedef short s16x8 __attribute__((ext_vector_type(8)));
typedef float f32x4 __attribute__((ext_vector_type(4)));

__device__ __forceinline__ short f2bf(float x) {
    __hip_bfloat16 h = __float2bfloat16(x);
    return *reinterpret_cast<short*>(&h);
}

// ---------------- embedding gather (writes bf16) ----------------
__global__ __launch_bounds__(256) void embed_kernel(
    const int* __restrict__ x,
    const float* __restrict__ t0, const float* __restrict__ t1,
    const float* __restrict__ t2, const float* __restrict__ t3,
    const float* __restrict__ t4, const float* __restrict__ t5,
    short* __restrict__ EMBb)
{
    int s = blockIdx.x;
    __shared__ int xi[6];
    if (threadIdx.x < 6) xi[threadIdx.x] = x[s * 6 + threadIdx.x];
    __syncthreads();
    for (int j = threadIdx.x; j < 768; j += 256) {
        int i, off, width; const float* t; float sc;
        if (j < 32)       { i = 0; off = 0;   t = t0; sc = 5.656854249f;  width = 32;  }
        else if (j < 160) { i = 1; off = 32;  t = t1; sc = 11.3137085f;   width = 128; }
        else if (j < 416) { i = 2; off = 160; t = t2; sc = 16.0f;         width = 256; }
        else if (j < 672) { i = 3; off = 416; t = t3; sc = 16.0f;         width = 256; }
        else if (j < 704) { i = 4; off = 672; t = t4; sc = 5.656854249f;  width = 32;  }
        else              { i = 5; off = 704; t = t5; sc = 8.0f;          width = 64;  }
        EMBb[s * 768 + j] = f2bf(t[xi[i] * width + (j - off)] * sc);
    }
}

// ---------------- weight transpose+convert: f32 [B][K][N] -> bf16 [B][N][K] ----
__global__ __launch_bounds__(256) void transpose_w(
    const float* __restrict__ in, short* __restrict__ out, int K, int N)
{
    __shared__ short t[64][66];
    const int b = blockIdx.z;
    const int n0 = blockIdx.x * 64, k0 = blockIdx.y * 64;
    const float* ip = in + (size_t)b * K * N;
    short* op = out + (size_t)b * K * N;
    const int c = threadIdx.x & 63, r0 = (threadIdx.x >> 6) * 16;
    #pragma unroll
    for (int i = 0; i < 16; ++i)
        t[c][r0 + i] = f2bf(ip[(size_t)(k0 + r0 + i) * N + n0 + c]);
    __syncthreads();
    #pragma unroll
    for (int i = 0; i < 16; ++i)
        op[(size_t)(n0 + r0 + i) * K + k0 + c] = t[r0 + i][c];
}

// ---------------- activation ----------------
__device__ __forceinline__ float apply_act(float v, int act) {
    if (act == ACT_PHI)       return (v > 0.0f) ? (v + 1.0f) : expf(v);
    else if (act == ACT_GELU) return 0.5f * v * (1.0f + erff(v * 0.70710678118654752f));
    return v;
}

// ---------------- 32x32-per-wave MFMA core ----------------
// ap/bp already offset to (row0+l15)*K + q*8 / (col0+l15)*K + q*8.
__device__ __forceinline__ void core32(
    const short* __restrict__ ap, const short* __restrict__ bp,
    int K, f32x4 acc[2][2])
{
    #pragma unroll 4
    for (int k0 = 0; k0 < K; k0 += 32) {
        s16x8 a0 = *(const s16x8*)(ap + k0);
        s16x8 a1 = *(const s16x8*)(ap + (size_t)16 * K + k0);
        s16x8 b0 = *(const s16x8*)(bp + k0);
        s16x8 b1 = *(const s16x8*)(bp + (size_t)16 * K + k0);
        acc[0][0] = __builtin_amdgcn_mfma_f32_16x16x32_bf16(a0, b0, acc[0][0], 0, 0, 0);
        acc[0][1] = __builtin_amdgcn_mfma_f32_16x16x32_bf16(a0, b1, acc[0][1], 0, 0, 0);
        acc[1][0] = __builtin_amdgcn_mfma_f32_16x16x32_bf16(a1, b0, acc[1][0], 0, 0, 0);
        acc[1][1] = __builtin_amdgcn_mfma_f32_16x16x32_bf16(a1, b1, acc[1][1], 0, 0, 0);
    }
}

// ---------------- generic GEMM, one 32x32 tile per wave, direct epilogue ----
__global__ __launch_bounds__(64) void gemm32(
    const short* __restrict__ A, const short* __restrict__ BT,
    const float* __restrict__ bias, const float* __restrict__ resid,
    float* __restrict__ Cf, short* __restrict__ Cbf,
    int N, int K, int act, int add_pe)
{
    const int row0 = blockIdx.y * 32, col0 = blockIdx.x * 32;
    const int lane = threadIdx.x, q = lane >> 4, l15 = lane & 15;
    f32x4 acc[2][2] = {};
    core32(A + (size_t)(row0 + l15) * K + q * 8,
           BT + (size_t)(col0 + l15) * K + q * 8, K, acc);

    #pragma unroll
    for (int ni = 0; ni < 2; ++ni) {
        int c = col0 + ni * 16 + l15;
        float bia = bias[c];
        #pragma unroll
        for (int mi = 0; mi < 2; ++mi) {
            #pragma unroll
            for (int rg = 0; rg < 4; ++rg) {
                int r = row0 + mi * 16 + q * 4 + rg;
                float v = apply_act(acc[mi][ni][rg] + bia, act);
                if (resid) v += resid[(size_t)r * N + c];
                if (add_pe) {
                    float freq = expf((float)(c & ~1) * (-9.210340371976184f / 512.0f));
                    float ang = (float)r * freq;
                    v += (c & 1) ? cosf(ang) : sinf(ang);
                }
                if (Cf)  Cf[(size_t)r * N + c] = v;
                if (Cbf) Cbf[(size_t)r * N + c] = f2bf(v);
            }
        }
    }
}

// ---------------- fused QKV: grid (48, 32); phi on Q,K ----------------
__global__ __launch_bounds__(64) void qkv32(
    const short* __restrict__ Hb,
    const short* __restrict__ qT, const short* __restrict__ kT, const short* __restrict__ vT,
    const float* __restrict__ bq, const float* __restrict__ bk, const float* __restrict__ bv,
    float* __restrict__ Qb, float* __restrict__ Kb, float* __restrict__ Vb)
{
    const int sel = blockIdx.x >> 4;
    const int col0 = (blockIdx.x & 15) * 32;
    const int row0 = blockIdx.y * 32;
    const short* BT   = (sel == 0) ? qT : (sel == 1) ? kT : vT;
    const float* bias = (sel == 0) ? bq : (sel == 1) ? bk : bv;
    float* C          = (sel == 0) ? Qb : (sel == 1) ? Kb : Vb;
    const bool phi = (sel < 2);

    const int lane = threadIdx.x, q = lane >> 4, l15 = lane & 15;
    f32x4 acc[2][2] = {};
    core32(Hb + (size_t)(row0 + l15) * DM + q * 8,
           BT + (size_t)(col0 + l15) * DM + q * 8, DM, acc);
    #pragma unroll
    for (int ni = 0; ni < 2; ++ni) {
        int c = col0 + ni * 16 + l15;
        float bia = bias[c];
        #pragma unroll
        for (int mi = 0; mi < 2; ++mi) {
            #pragma unroll
            for (int rg = 0; rg < 4; ++rg) {
                int r = row0 + mi * 16 + q * 4 + rg;
                float v = acc[mi][ni][rg] + bia;
                if (phi) v = (v > 0.0f) ? (v + 1.0f) : expf(v);
                C[(size_t)r * DM + c] = v;
            }
        }
    }
}

// ---------------- chunk stats: per (head, chunk) KV_c = K_c^T V_c, ksum_c ----------------
__global__ __launch_bounds__(256) void chunk_stats_kernel(
    const float* __restrict__ Kb, const float* __restrict__ Vb,
    float* __restrict__ KVC, float* __restrict__ KSC)
{
    const int h = blockIdx.x >> 4, c = blockIdx.x & 15;
    const int tid = threadIdx.x;
    __shared__ float Ks[CHUNK][64];
    __shared__ float Vs[CHUNK][64];
    for (int i = tid; i < CHUNK * 64; i += 256) {
        int r = i >> 6, cc = i & 63;
        Ks[r][cc] = Kb[(size_t)(c * CHUNK + r) * DM + h * 64 + cc];
        Vs[r][cc] = Vb[(size_t)(c * CHUNK + r) * DM + h * 64 + cc];
    }
    __syncthreads();
    const int e = tid & 63, dg = tid >> 6;
    float acc[16] = {};
    for (int t = 0; t < CHUNK; ++t) {
        float vv = Vs[t][e];
        #pragma unroll
        for (int i = 0; i < 16; ++i) acc[i] += Ks[t][dg * 16 + i] * vv;
    }
    float* out = KVC + ((size_t)(c * NH + h)) * 4096;
    #pragma unroll
    for (int i = 0; i < 16; ++i) out[(dg * 16 + i) * 64 + e] = acc[i];
    if (tid < 64) {
        float s = 0.0f;
        for (int t = 0; t < CHUNK; ++t) s += Ks[t][tid];
        KSC[(size_t)(c * NH + h) * 64 + tid] = s;
    }
}

// ---------------- attention output per (head, chunk): inline prefix + intra ----
__global__ __launch_bounds__(256) void attn_out_kernel(
    const float* __restrict__ Qb, const float* __restrict__ Kb,
    const float* __restrict__ Vb, const float* __restrict__ KVC,
    const float* __restrict__ KSC, short* __restrict__ Ab)
{
    const int h = blockIdx.x >> 4, c = blockIdx.x & 15;
    const int tid = threadIdx.x;
    __shared__ float Qs[64][65];
    __shared__ float B1[64][64];   // phase 1: kv prefix state; phase 2: K chunk
    __shared__ float B2[64][64];   // phase 2: V chunk
    __shared__ float KSs[64];

    // load Q chunk
    for (int i = tid; i < 4096; i += 256) {
        int r = i >> 6, cc = i & 63;
        Qs[r][cc] = Qb[(size_t)(c * CHUNK + r) * DM + h * 64 + cc];
    }
    // build prefix state sum_{c'<c} KVC[c'] into B1, and KSs
    {
        float accv[16];
        #pragma unroll
        for (int j = 0; j < 16; ++j) accv[j] = 0.0f;
        for (int cp = 0; cp < c; ++cp) {
            const float* src = KVC + ((size_t)(cp * NH + h)) * 4096;
            #pragma unroll
            for (int j = 0; j < 16; ++j) accv[j] += src[tid + j * 256];
        }
        #pragma unroll
        for (int j = 0; j < 16; ++j) {
            int idx = tid + j * 256;
            B1[idx >> 6][idx & 63] = accv[j];
        }
        if (tid < 64) {
            float s = 0.0f;
            for (int cp = 0; cp < c; ++cp) s += KSC[(size_t)(cp * NH + h) * 64 + tid];
            KSs[tid] = s;
        }
    }
    __syncthreads();

    const int s = tid >> 2, e0 = (tid & 3) * 16;
    float acc[16] = {};
    float den = 0.0f;

    // inter-chunk (state) part
    for (int d = 0; d < 64; ++d) {
        float qd = Qs[s][d];
        den += qd * KSs[d];
        #pragma unroll
        for (int j = 0; j < 16; ++j) acc[j] += qd * B1[d][e0 + j];
    }
    __syncthreads();
    // load K,V chunk
    for (int i = tid; i < 4096; i += 256) {
        int r = i >> 6, cc = i & 63;
        size_t g = (size_t)(c * CHUNK + r) * DM + h * 64 + cc;
        B1[r][cc] = Kb[g];
        B2[r][cc] = Vb[g];
    }
    __syncthreads();
    // intra-chunk causal part
    for (int t2 = 0; t2 <= s; ++t2) {
        float sc = 0.0f;
        #pragma unroll
        for (int d = 0; d < 64; ++d) sc += Qs[s][d] * B1[t2][d];
        den += sc;
        #pragma unroll
        for (int j = 0; j < 16; ++j) acc[j] += sc * B2[t2][e0 + j];
    }
    float z = 1.0f / (den + 1e-6f);
    short* out = Ab + (size_t)(c * CHUNK + s) * DM + h * 64 + e0;
    #pragma unroll
    for (int j = 0; j < 16; ++j) out[j] = f2bf(acc[j] * z);
}

// ---------------- layernorm (fp32 out + optional bf16 mirror) ----------------
__device__ __forceinline__ float block_reduce_sum(float v, float* smem)
{
    #pragma unroll
    for (int o = 32; o > 0; o >>= 1) v += __shfl_down(v, o, 64);
    int w = threadIdx.x >> 6;
    if ((threadIdx.x & 63) == 0) smem[w] = v;
    __syncthreads();
    v = smem[0] + smem[1] + smem[2] + smem[3];
    __syncthreads();
    return v;
}

__global__ __launch_bounds__(256) void ln_kernel(
    const float* __restrict__ X, const float* __restrict__ g,
    const float* __restrict__ b, float* __restrict__ O, short* __restrict__ Ob)
{
    __shared__ float red[4];
    const int row = blockIdx.x;
    const float* x = X + (size_t)row * DM;
    const int t = threadIdx.x;
    float v0 = x[t], v1 = x[t + 256];
    float mean = block_reduce_sum(v0 + v1, red) * (1.0f / 512.0f);
    float d0 = v0 - mean, d1 = v1 - mean;
    float var = block_reduce_sum(d0 * d0 + d1 * d1, red) * (1.0f / 512.0f);
    float rs = 1.0f / sqrtf(var + 1e-5f);
    float o0 = d0 * rs * g[t] + b[t];
    float o1 = d1 * rs * g[t + 256] + b[t + 256];
    O[(size_t)row * DM + t]       = o0;
    O[(size_t)row * DM + t + 256] = o1;
    if (Ob) {
        Ob[(size_t)row * DM + t]       = f2bf(o0);
        Ob[(size_t)row * DM + t + 256] = f2bf(o1);
    }
}

// ---------------- emotion head: [1024,512] @ [512,8] + b ----------------
__global__ __launch_bounds__(256) void proj_emo_kernel(
    const float* __restrict__ HF, const float* __restrict__ pw,
    const float* __restrict__ pb, float* __restrict__ out)
{
    int idx = blockIdx.x * 256 + threadIdx.x;
    int r = idx >> 3, e = idx & 7;
    float acc = pb[e];
    const float* h = HF + (size_t)r * DM;
    for (int d = 0; d < DM; ++d) acc += h[d] * pw[d * 8 + e];
    out[idx] = acc;
}

// ---------------------------------------------------------------------------
extern "C" void kernel_launch(void* const* d_in, const int* in_sizes, int n_in,
                              void* d_out, int out_size, void* d_ws, size_t ws_size,
                              hipStream_t stream)
{
    const int*   x    = (const int*)d_in[0];
    const float* e0   = (const float*)d_in[1];
    const float* e1   = (const float*)d_in[2];
    const float* e2   = (const float*)d_in[3];
    const float* e3   = (const float*)d_in[4];
    const float* e4   = (const float*)d_in[5];
    const float* e5   = (const float*)d_in[6];
    const float* in_w = (const float*)d_in[7];
    const float* in_b = (const float*)d_in[8];
    const float* wq   = (const float*)d_in[9];
    const float* bq   = (const float*)d_in[10];
    const float* wk   = (const float*)d_in[11];
    const float* bk   = (const float*)d_in[12];
    const float* wv   = (const float*)d_in[13];
    const float* bv   = (const float*)d_in[14];
    const float* wo   = (const float*)d_in[15];
    const float* bo   = (const float*)d_in[16];
    const float* g1   = (const float*)d_in[17];
    const float* be1  = (const float*)d_in[18];
    const float* w1   = (const float*)d_in[19];
    const float* b1   = (const float*)d_in[20];
    const float* w2   = (const float*)d_in[21];
    const float* b2   = (const float*)d_in[22];
    const float* g2   = (const float*)d_in[23];
    const float* be2  = (const float*)d_in[24];
    const float* gf   = (const float*)d_in[25];
    const float* bfin = (const float*)d_in[26];
    const float* pw   = (const float*)d_in[27];
    const float* pb   = (const float*)d_in[28];
    float* outp = (float*)d_out;

    // ---- workspace layout (dedicated buffers, no f32-region aliasing) ----
    float* ws = (float*)d_ws;
    float* H    = ws;                  // 1024x512 f32
    float* Y    = ws + 524288;         // 1024x512 f32
    float* Qb   = ws + 1048576;
    float* Kb   = ws + 1572864;
    float* Vb   = ws + 2097152;
    float* KVC  = ws + 2621440;        // 16*8*4096 = 524288
    float* KSC  = ws + 3145728;        // 8192 (f32 end: 3153920 floats)
    short* sb   = (short*)(ws + 3153920);
    short* Hb   = sb;                  // 1024x512
    short* Ab   = sb + 524288;         // 1024x512
    short* FFb  = sb + 1048576;        // 1024x2048
    short* EMBb = FFb;                 // 1024x768 (alias: dead before ffn1)
    // bf16 W^T arena [N][K]
    short* inT  = sb + 3145728;        // [512][768]
    short* qT   = inT + 393216;        // [12][512][512]
    short* kT   = qT + 3145728;
    short* vT   = kT + 3145728;
    short* oT   = vT + 3145728;
    short* w1T  = oT + 3145728;        // [12][2048][512]
    short* w2T  = w1T + 12582912;      // [12][512][2048]  (total ~90.8 MB)

    const dim3 blk256(256), blk64(64);

    // ---- weight transpose+convert ----
    transpose_w<<<dim3(8, 12, 1),  blk256, 0, stream>>>(in_w, inT, 768, DM);
    transpose_w<<<dim3(8, 8, 12),  blk256, 0, stream>>>(wq, qT, DM, DM);
    transpose_w<<<dim3(8, 8, 12),  blk256, 0, stream>>>(wk, kT, DM, DM);
    transpose_w<<<dim3(8, 8, 12),  blk256, 0, stream>>>(wv, vT, DM, DM);
    transpose_w<<<dim3(8, 8, 12),  blk256, 0, stream>>>(wo, oT, DM, DM);
    transpose_w<<<dim3(32, 8, 12), blk256, 0, stream>>>(w1, w1T, DM, DFF);
    transpose_w<<<dim3(8, 32, 12), blk256, 0, stream>>>(w2, w2T, DFF, DM);

    embed_kernel<<<S_LEN, blk256, 0, stream>>>(x, e0, e1, e2, e3, e4, e5, EMBb);
    // in-proj: EMBb @ in_w + in_b + PE -> H (f32) and Hb (bf16)
    gemm32<<<dim3(16, 32), blk64, 0, stream>>>(EMBb, inT, in_b, nullptr,
                                               H, Hb, DM, 768, ACT_NONE, 1);

    for (int l = 0; l < NLAYER; ++l) {
        const short* qT_l = qT + (size_t)l * DM * DM;
        const short* kT_l = kT + (size_t)l * DM * DM;
        const short* vT_l = vT + (size_t)l * DM * DM;
        const short* oT_l = oT + (size_t)l * DM * DM;
        const short* w1T_l = w1T + (size_t)l * DM * DFF;
        const short* w2T_l = w2T + (size_t)l * DM * DFF;
        const float* bq_l = bq + l * DM;  const float* bk_l = bk + l * DM;
        const float* bv_l = bv + l * DM;  const float* bo_l = bo + l * DM;
        const float* b1_l = b1 + l * DFF; const float* b2_l = b2 + l * DM;

        qkv32<<<dim3(48, 32), blk64, 0, stream>>>(Hb, qT_l, kT_l, vT_l,
                                                  bq_l, bk_l, bv_l, Qb, Kb, Vb);

        chunk_stats_kernel<<<NCH * NH, blk256, 0, stream>>>(Kb, Vb, KVC, KSC);
        attn_out_kernel<<<NCH * NH, blk256, 0, stream>>>(Qb, Kb, Vb, KVC, KSC, Ab);

        // wo: Ab @ wo + bo + resid(H) -> Y (f32); then LN -> H, Hb
        gemm32<<<dim3(16, 32), blk64, 0, stream>>>(Ab, oT_l, bo_l, H,
                                                   Y, nullptr, DM, DM, ACT_NONE, 0);
        ln_kernel<<<S_LEN, blk256, 0, stream>>>(Y, g1 + l * DM, be1 + l * DM, H, Hb);

        // ffn1: Hb @ w1 + b1, GELU -> FFb (bf16)
        gemm32<<<dim3(64, 32), blk64, 0, stream>>>(Hb, w1T_l, b1_l, nullptr,
                                                   nullptr, FFb, DFF, DM, ACT_GELU, 0);
        // ffn2: FFb @ w2 + b2 + resid(H) -> Y (f32); then LN -> H, Hb
        gemm32<<<dim3(16, 32), blk64, 0, stream>>>(FFb, w2T_l, b2_l, H,
                                                   Y, nullptr, DM, DFF, ACT_NONE, 0);
        ln_kernel<<<S_LEN, blk256, 0, stream>>>(Y, g2 + l * DM, be2 + l * DM, H, Hb);
    }

    // final norm -> d_out (f32 h), then emotion head
    ln_kernel<<<S_LEN, blk256, 0, stream>>>(H, gf, bfin, outp, nullptr);
    proj_emo_kernel<<<8192 / 256, blk256, 0, stream>>>(outp, pw, pb, outp + 524288);
}